// Round 1
// baseline (489.254 us; speedup 1.0000x reference)
//
#include <hip/hip_runtime.h>
#include <math.h>

#define NB 8
#define S 2048
#define D 128
#define ROWS 32          // query rows per block
#define TK 64            // keys per LDS tile
#define NT (S / TK)      // 32 tiles
#define CAP 120          // candidate capacity per row
#define NTH 256
#define ALPHA_M1 0.5f    // alpha - 1
#define HI_OFF 0.022097086912079608f  // d^(1-alpha) = 2048^-0.5
#define NITER 50

// entmax-1.5 attention. Support lemma: tau >= mx - 1 always (lo starts there and
// only increases), so any x <= mx-1 has p == 0 exactly -> bisection + PV only
// need candidates with x > runningmax - 1 (superset of support; extras add
// exact fp32 zeros, matching the reference sum).
__global__ __launch_bounds__(NTH, 2) void entmax_attn_kernel(
    const float* __restrict__ query,
    const float* __restrict__ key,
    const float* __restrict__ value,
    float* __restrict__ out)
{
    __shared__ float4 sK[TK * 32];        // 32 KB, XOR-swizzled K tile
    __shared__ float4 sQ[ROWS * 32];      // 16 KB, pre-scaled by 0.5
    __shared__ int    cIdx[ROWS][CAP];    // 15 KB
    __shared__ float  cVal[ROWS][CAP];    // 15 KB
    __shared__ int    ccnt[ROWS];

    const int tid = threadIdx.x;
    const int bid = blockIdx.x;
    const int b   = bid >> 6;             // 64 row-blocks per batch
    const int rb  = bid & 63;

    const float4* Qg = (const float4*)(query + ((size_t)b * S + (size_t)rb * ROWS) * D);
    const float4* Kg = (const float4*)(key + (size_t)b * S * D);

    // stage Q, scaled by (alpha-1) = 0.5 (exact power-of-2 scale)
    #pragma unroll
    for (int i = 0; i < 4; i++) {
        int f = tid + NTH * i;            // 1024 float4
        float4 v = Qg[f];
        v.x *= ALPHA_M1; v.y *= ALPHA_M1; v.z *= ALPHA_M1; v.w *= ALPHA_M1;
        sQ[f] = v;
    }
    if (tid < ROWS) ccnt[tid] = 0;

    const int kg  = tid & 31;             // key position within tile (keys kg, kg+32)
    const int rg  = tid >> 5;             // row group (4 rows)
    const int swz = kg & 7;

    float rm[4];                          // running max per owned row (wave-group uniform)
    #pragma unroll
    for (int i = 0; i < 4; i++) rm[i] = -3.0e38f;

    // prefetch tile 0 into registers
    float4 pre[8];
    #pragma unroll
    for (int i = 0; i < 8; i++) pre[i] = Kg[tid + NTH * i];

    for (int t = 0; t < NT; t++) {
        // write staged tile to LDS (swizzled)
        #pragma unroll
        for (int i = 0; i < 8; i++) {
            int f = tid + NTH * i;
            int kl = f >> 5, dc = f & 31;
            sK[kl * 32 + (dc ^ (kl & 7))] = pre[i];
        }
        // issue next tile's loads (latency hides under compute)
        if (t + 1 < NT) {
            #pragma unroll
            for (int i = 0; i < 8; i++) pre[i] = Kg[(t + 1) * (TK * 32) + tid + NTH * i];
        }
        __syncthreads();

        float acc[4][2] = {{0.f,0.f},{0.f,0.f},{0.f,0.f},{0.f,0.f}};
        #pragma unroll 8
        for (int dc = 0; dc < 32; dc++) {
            int sw = dc ^ swz;
            float4 k0 = sK[kg * 32 + sw];
            float4 k1 = sK[(kg + 32) * 32 + sw];
            #pragma unroll
            for (int i = 0; i < 4; i++) {
                float4 qv = sQ[(rg * 4 + i) * 32 + dc];
                acc[i][0] = fmaf(qv.x, k0.x, acc[i][0]);
                acc[i][0] = fmaf(qv.y, k0.y, acc[i][0]);
                acc[i][0] = fmaf(qv.z, k0.z, acc[i][0]);
                acc[i][0] = fmaf(qv.w, k0.w, acc[i][0]);
                acc[i][1] = fmaf(qv.x, k1.x, acc[i][1]);
                acc[i][1] = fmaf(qv.y, k1.y, acc[i][1]);
                acc[i][1] = fmaf(qv.z, k1.z, acc[i][1]);
                acc[i][1] = fmaf(qv.w, k1.w, acc[i][1]);
            }
        }

        // per-row running max (32-lane butterfly; rows are wave-private) + candidate push
        #pragma unroll
        for (int i = 0; i < 4; i++) {
            float m = fmaxf(acc[i][0], acc[i][1]);
            m = fmaxf(m, __shfl_xor(m, 1));
            m = fmaxf(m, __shfl_xor(m, 2));
            m = fmaxf(m, __shfl_xor(m, 4));
            m = fmaxf(m, __shfl_xor(m, 8));
            m = fmaxf(m, __shfl_xor(m, 16));
            rm[i] = fmaxf(rm[i], m);
            float thr = rm[i] - 1.0f;
            #pragma unroll
            for (int j = 0; j < 2; j++) {
                if (acc[i][j] > thr) {
                    int row = rg * 4 + i;
                    int slot = atomicAdd(&ccnt[row], 1);
                    if (slot < CAP) {
                        cIdx[row][slot] = t * TK + kg + 32 * j;
                        cVal[row][slot] = acc[i][j];
                    }
                }
            }
        }
        __syncthreads();
    }

    // ---- bisection + sparse PV: wave wid owns rows wid*8 .. wid*8+7 ----
    const int wid  = tid >> 6;
    const int lane = tid & 63;
    const float* Vb = value + (size_t)b * S * D;
    float* Ob = out + ((size_t)b * S + (size_t)rb * ROWS) * D;

    #pragma unroll
    for (int r8 = 0; r8 < 8; r8++) {
        int row = wid * 8 + r8;
        int n = min(ccnt[row], CAP);
        float mx = __shfl(rm[r8 & 3], (r8 & 4) ? 32 : 0);

        float lo = mx - 1.0f;
        float hi = mx - HI_OFF;
        for (int it = 0; it < NITER; it++) {
            float mid = 0.5f * (lo + hi);
            float s = 0.0f;
            for (int c = lane; c < n; c += 64) {
                float tv = fmaxf(cVal[row][c] - mid, 0.0f);
                s = fmaf(tv, tv, s);
            }
            s += __shfl_xor(s, 1);
            s += __shfl_xor(s, 2);
            s += __shfl_xor(s, 4);
            s += __shfl_xor(s, 8);
            s += __shfl_xor(s, 16);
            s += __shfl_xor(s, 32);
            if (s - 1.0f >= 0.0f) lo = mid; else hi = mid;
        }
        float tau = 0.5f * (lo + hi);

        // unnormalized p, write back, and total Z
        float z = 0.0f;
        for (int c = lane; c < n; c += 64) {
            float tv = fmaxf(cVal[row][c] - tau, 0.0f);
            float p = tv * tv;
            cVal[row][c] = p;
            z += p;
        }
        z += __shfl_xor(z, 1);
        z += __shfl_xor(z, 2);
        z += __shfl_xor(z, 4);
        z += __shfl_xor(z, 8);
        z += __shfl_xor(z, 16);
        z += __shfl_xor(z, 32);
        float zinv = 1.0f / z;

        // sparse PV: lanes cover D=128 as float2; unroll candidates x4 for MLP
        float2 o = make_float2(0.0f, 0.0f);
        int c = 0;
        for (; c + 4 <= n; c += 4) {
            float p0 = cVal[row][c+0], p1 = cVal[row][c+1];
            float p2 = cVal[row][c+2], p3 = cVal[row][c+3];
            int i0 = cIdx[row][c+0], i1 = cIdx[row][c+1];
            int i2 = cIdx[row][c+2], i3 = cIdx[row][c+3];
            float2 a0 = ((const float2*)(Vb + (size_t)i0 * D))[lane];
            float2 a1 = ((const float2*)(Vb + (size_t)i1 * D))[lane];
            float2 a2 = ((const float2*)(Vb + (size_t)i2 * D))[lane];
            float2 a3 = ((const float2*)(Vb + (size_t)i3 * D))[lane];
            o.x = fmaf(p0, a0.x, o.x); o.y = fmaf(p0, a0.y, o.y);
            o.x = fmaf(p1, a1.x, o.x); o.y = fmaf(p1, a1.y, o.y);
            o.x = fmaf(p2, a2.x, o.x); o.y = fmaf(p2, a2.y, o.y);
            o.x = fmaf(p3, a3.x, o.x); o.y = fmaf(p3, a3.y, o.y);
        }
        for (; c < n; c++) {
            float p = cVal[row][c];
            int ii = cIdx[row][c];
            float2 a = ((const float2*)(Vb + (size_t)ii * D))[lane];
            o.x = fmaf(p, a.x, o.x); o.y = fmaf(p, a.y, o.y);
        }
        o.x *= zinv; o.y *= zinv;
        ((float2*)(Ob + (size_t)row * D))[lane] = o;
    }
}

extern "C" void kernel_launch(void* const* d_in, const int* in_sizes, int n_in,
                              void* d_out, int out_size, void* d_ws, size_t ws_size,
                              hipStream_t stream) {
    const float* q = (const float*)d_in[0];
    const float* k = (const float*)d_in[1];
    const float* v = (const float*)d_in[2];
    float* o = (float*)d_out;
    dim3 grid(NB * (S / ROWS));   // 8 * 64 = 512 blocks
    dim3 block(NTH);
    hipLaunchKernelGGL(entmax_attn_kernel, grid, block, 0, stream, q, k, v, o);
}

// Round 2
// 147.892 us; speedup vs baseline: 3.3082x; 3.3082x over previous
//
#include <hip/hip_runtime.h>
#include <math.h>

#define NB 8
#define S 2048
#define D 128
#define ROWS 32          // q-rows per block
#define CAP 64           // candidate capacity per row (must equal 64 for ballot compaction)
#define NTH 256
#define WKEYS 512        // keys per wave
#define CHUNK 32         // keys per MFMA chunk
#define NCK (WKEYS / CHUNK)   // 16
#define MARGIN 1.6f      // 1.0 (support lemma) + 0.6 (bf16 screening error bound 2*0.24)

typedef __attribute__((ext_vector_type(8))) short bf16x8;
typedef __attribute__((ext_vector_type(4))) float f32x4;

__device__ __forceinline__ unsigned fmap(float f) {
    unsigned u = __float_as_uint(f);
    return (u & 0x80000000u) ? ~u : (u | 0x80000000u);
}
__device__ __forceinline__ float funmap(unsigned k) {
    return (k & 0x80000000u) ? __uint_as_float(k ^ 0x80000000u) : __uint_as_float(~k);
}
__device__ __forceinline__ unsigned short f2bf(float f) {   // RNE bf16
    unsigned u = __float_as_uint(f);
    return (unsigned short)((u + 0x7fffu + ((u >> 16) & 1u)) >> 16);
}

// ---------------- pre-pass: fp32 -> bf16 (Q scaled by alpha-1 = 0.5, exact) ---------------
__global__ void convert_kernel(const float* __restrict__ q, const float* __restrict__ k,
                               unsigned short* __restrict__ qb, unsigned short* __restrict__ kb) {
    int i = blockIdx.x * NTH + threadIdx.x;     // 524288 threads, float4 granularity
    float4 qv = ((const float4*)q)[i];
    float4 kv = ((const float4*)k)[i];
    ushort4 qo, ko;
    qo.x = f2bf(0.5f * qv.x); qo.y = f2bf(0.5f * qv.y); qo.z = f2bf(0.5f * qv.z); qo.w = f2bf(0.5f * qv.w);
    ko.x = f2bf(kv.x);        ko.y = f2bf(kv.y);        ko.z = f2bf(kv.z);        ko.w = f2bf(kv.w);
    ((ushort4*)qb)[i] = qo;
    ((ushort4*)kb)[i] = ko;
}

// ---------------- main: MFMA screening + exact rescore + closed-form entmax + sparse PV ----
__global__ __launch_bounds__(NTH, 2) void entmax_mfma_kernel(
    const float* __restrict__ query, const float* __restrict__ key,
    const float* __restrict__ value, float* __restrict__ out,
    const unsigned short* __restrict__ qb, const unsigned short* __restrict__ kb)
{
    __shared__ float cVal[ROWS][CAP];            // 8 KB
    __shared__ unsigned short cIdx[ROWS][CAP];   // 4 KB
    __shared__ unsigned rmS[ROWS];
    __shared__ int ccnt[ROWS];

    const int tid  = threadIdx.x;
    const int b    = blockIdx.x & 7;             // batch -> XCD (round-robin dispatch)
    const int rb   = blockIdx.x >> 3;            // row-block within batch
    const int w    = tid >> 6;                   // wave 0..3
    const int lane = tid & 63;
    const int g    = lane >> 4;                  // k-group for MFMA frags
    const int l15  = lane & 15;

    if (tid < ROWS) { rmS[tid] = fmap(-3.0e38f); ccnt[tid] = 0; }
    __syncthreads();

    // ---- A-fragments: all of this block's Q' held in registers for the whole kernel ----
    // layout per m97/gemm_bt: lane reads matrix-row (l&15), k-bytes (s*64 + g*16)
    const uint4* Qb4 = (const uint4*)qb + (size_t)(b * S + rb * ROWS) * 16;
    uint4 aq[2][4];
    #pragma unroll
    for (int rt = 0; rt < 2; rt++)
        #pragma unroll
        for (int s = 0; s < 4; s++)
            aq[rt][s] = Qb4[(rt * 16 + l15) * 16 + s * 4 + g];

    const uint4* Kb4 = (const uint4*)kb + (size_t)(b * S) * 16;
    const int key0w = w * WKEYS;

    float rmr[2][4];                              // per-wave running row max (bf16 scores)
    #pragma unroll
    for (int rt = 0; rt < 2; rt++)
        #pragma unroll
        for (int j = 0; j < 4; j++) rmr[rt][j] = -3.0e38f;

    uint4 bb0[8], bb1[8];

#define LOADB(dst, ck_)                                                              \
    {                                                                                \
        int kbase_ = key0w + (ck_) * CHUNK;                                          \
        _Pragma("unroll")                                                            \
        for (int kt = 0; kt < 2; kt++)                                               \
            _Pragma("unroll")                                                        \
            for (int s = 0; s < 4; s++)                                              \
                dst[kt * 4 + s] = Kb4[(size_t)(kbase_ + kt * 16 + l15) * 16 + s * 4 + g]; \
    }

#define CHUNK_BODY(cur, nxt, ck_)                                                    \
    {                                                                                \
        if ((ck_) + 1 < NCK) LOADB(nxt, (ck_) + 1);                                  \
        f32x4 acc[2][2];                                                             \
        _Pragma("unroll")                                                            \
        for (int rt = 0; rt < 2; rt++)                                               \
            _Pragma("unroll")                                                        \
            for (int kt = 0; kt < 2; kt++) acc[rt][kt] = (f32x4){0.f, 0.f, 0.f, 0.f}; \
        _Pragma("unroll")                                                            \
        for (int s = 0; s < 4; s++) {                                                \
            bf16x8 fb0 = *reinterpret_cast<const bf16x8*>(&cur[0 * 4 + s]);          \
            bf16x8 fb1 = *reinterpret_cast<const bf16x8*>(&cur[1 * 4 + s]);          \
            _Pragma("unroll")                                                        \
            for (int rt = 0; rt < 2; rt++) {                                         \
                bf16x8 fa = *reinterpret_cast<const bf16x8*>(&aq[rt][s]);            \
                acc[rt][0] = __builtin_amdgcn_mfma_f32_16x16x32_bf16(fa, fb0, acc[rt][0], 0, 0, 0); \
                acc[rt][1] = __builtin_amdgcn_mfma_f32_16x16x32_bf16(fa, fb1, acc[rt][1], 0, 0, 0); \
            }                                                                        \
        }                                                                            \
        /* C layout (m89-verified): row = rt*16 + g*4 + j, key-col = kt*16 + l15 */  \
        float red[2][4];                                                             \
        _Pragma("unroll")                                                            \
        for (int rt = 0; rt < 2; rt++)                                               \
            _Pragma("unroll")                                                        \
            for (int j = 0; j < 4; j++) red[rt][j] = fmaxf(acc[rt][0][j], acc[rt][1][j]); \
        _Pragma("unroll")                                                            \
        for (int m = 1; m <= 8; m <<= 1)                                             \
            _Pragma("unroll")                                                        \
            for (int rt = 0; rt < 2; rt++)                                           \
                _Pragma("unroll")                                                    \
                for (int j = 0; j < 4; j++)                                          \
                    red[rt][j] = fmaxf(red[rt][j], __shfl_xor(red[rt][j], m));       \
        bool up[2][4];                                                               \
        _Pragma("unroll")                                                            \
        for (int rt = 0; rt < 2; rt++)                                               \
            _Pragma("unroll")                                                        \
            for (int j = 0; j < 4; j++) {                                            \
                up[rt][j] = red[rt][j] > rmr[rt][j];                                 \
                rmr[rt][j] = fmaxf(rmr[rt][j], red[rt][j]);                          \
            }                                                                        \
        if (l15 == 0) {                                                              \
            _Pragma("unroll")                                                        \
            for (int rt = 0; rt < 2; rt++)                                           \
                _Pragma("unroll")                                                    \
                for (int j = 0; j < 4; j++)                                          \
                    if (up[rt][j]) atomicMax(&rmS[rt * 16 + g * 4 + j], fmap(rmr[rt][j])); \
        }                                                                            \
        float thr[2][4];                                                             \
        _Pragma("unroll")                                                            \
        for (int rt = 0; rt < 2; rt++)                                               \
            _Pragma("unroll")                                                        \
            for (int j = 0; j < 4; j++)                                              \
                thr[rt][j] = fmaxf(rmr[rt][j], funmap(rmS[rt * 16 + g * 4 + j])) - MARGIN; \
        int kb0_ = key0w + (ck_) * CHUNK + l15;                                      \
        _Pragma("unroll")                                                            \
        for (int rt = 0; rt < 2; rt++)                                               \
            _Pragma("unroll")                                                        \
            for (int kt = 0; kt < 2; kt++)                                           \
                _Pragma("unroll")                                                    \
                for (int j = 0; j < 4; j++) {                                        \
                    float v_ = acc[rt][kt][j];                                       \
                    if (v_ > thr[rt][j]) {                                           \
                        int row_ = rt * 16 + g * 4 + j;                              \
                        int slot_ = atomicAdd(&ccnt[row_], 1);                       \
                        if (slot_ < CAP) {                                           \
                            cVal[row_][slot_] = v_;                                  \
                            cIdx[row_][slot_] = (unsigned short)(kb0_ + kt * 16);    \
                        }                                                            \
                    }                                                                \
                }                                                                    \
    }

    LOADB(bb0, 0);
    for (int t = 0; t < NCK / 2; t++) {
        CHUNK_BODY(bb0, bb1, 2 * t);
        CHUNK_BODY(bb1, bb0, 2 * t + 1);
    }

    // final cross-wave max merge
    if (l15 == 0) {
        #pragma unroll
        for (int rt = 0; rt < 2; rt++)
            #pragma unroll
            for (int j = 0; j < 4; j++)
                atomicMax(&rmS[rt * 16 + g * 4 + j], fmap(rmr[rt][j]));
    }
    __syncthreads();

    // ---------------- epilogue: wave w owns rows w*8 .. w*8+8 ----------------
    const float* Qg = query + (size_t)(b * S + rb * ROWS) * D;
    const float* Kg = key   + (size_t)b * S * D;
    const float* Vg = value + (size_t)b * S * D;
    float* Og = out + (size_t)(b * S + rb * ROWS) * D;

    for (int r8 = 0; r8 < 8; r8++) {
        int row = w * 8 + r8;
        int n = min(ccnt[row], CAP);
        float thrc = funmap(rmS[row]) - MARGIN;

        // wave-parallel compaction against the FINAL bf16 max (lane == slot, CAP == 64)
        float v = (lane < n) ? cVal[row][lane] : -3.0e38f;
        unsigned short id = (lane < n) ? cIdx[row][lane] : 0;
        unsigned long long mk = __ballot(v > thrc);
        int nc = __popcll(mk);
        int pos = __popcll(mk & ((1ull << lane) - 1ull));
        if (v > thrc) cIdx[row][pos] = id;   // reads already in regs; wave-lockstep safe

        // exact fp32 rescore: 8 lanes per candidate, 16 d-elems per lane
        int c0 = lane >> 3;
        int dl = lane & 7;
        float4 q4[4];
        #pragma unroll
        for (int i = 0; i < 4; i++)
            q4[i] = ((const float4*)(Qg + (size_t)row * D))[dl * 4 + i];
        for (int cc = c0; cc < nc; cc += 8) {
            int ky = cIdx[row][cc];
            float s = 0.f;
            #pragma unroll
            for (int i = 0; i < 4; i++) {
                float4 k4 = ((const float4*)(Kg + (size_t)ky * D))[dl * 4 + i];
                s = fmaf(q4[i].x, k4.x, s);
                s = fmaf(q4[i].y, k4.y, s);
                s = fmaf(q4[i].z, k4.z, s);
                s = fmaf(q4[i].w, k4.w, s);
            }
            s += __shfl_xor(s, 1);
            s += __shfl_xor(s, 2);
            s += __shfl_xor(s, 4);
            if (dl == 0) cVal[row][cc] = 0.5f * s;   // x = (alpha-1) * z, exact fp32
        }

        // closed-form entmax-1.5 threshold (lane 0): sort desc, tau_k = (S1 - sqrt(S1^2 - k(S2-1)))/k
        float tauf = 0.f;
        if (lane == 0) {
            for (int i = 0; i < nc - 1; i++) {            // selection sort (nc tiny)
                int mi = i; float mv = cVal[row][i];
                for (int j2 = i + 1; j2 < nc; j2++)
                    if (cVal[row][j2] > mv) { mv = cVal[row][j2]; mi = j2; }
                if (mi != i) {
                    float tv = cVal[row][i]; cVal[row][i] = cVal[row][mi]; cVal[row][mi] = tv;
                    unsigned short ti = cIdx[row][i]; cIdx[row][i] = cIdx[row][mi]; cIdx[row][mi] = ti;
                }
            }
            double S1 = 0.0, S2 = 0.0;
            double tau = (double)cVal[row][0] - 1.0;      // k=1 solution (always valid)
            for (int k2 = 1; k2 <= nc; k2++) {
                double xk = (double)cVal[row][k2 - 1];
                S1 += xk; S2 += xk * xk;
                double disc = S1 * S1 - (double)k2 * (S2 - 1.0);
                if (disc >= 0.0) {
                    double tk = (S1 - sqrt(disc)) / (double)k2;
                    if (xk > tk) tau = tk;                // keep largest valid k
                }
            }
            tauf = (float)tau;
        }
        tauf = __shfl(tauf, 0);

        // p = max(x - tau, 0)^2, normalize, sparse PV (lanes cover D as float2)
        float Z = 0.f;
        float2 o = make_float2(0.f, 0.f);
        for (int cc = 0; cc < nc; cc++) {
            float x = cVal[row][cc];
            float t = fmaxf(x - tauf, 0.f);
            float p = t * t;
            Z += p;
            if (t > 0.f) {
                int ky = cIdx[row][cc];
                float2 a = ((const float2*)(Vg + (size_t)ky * D))[lane];
                o.x = fmaf(p, a.x, o.x);
                o.y = fmaf(p, a.y, o.y);
            }
        }
        float zi = 1.0f / Z;
        o.x *= zi; o.y *= zi;
        ((float2*)(Og + (size_t)row * D))[lane] = o;
    }
}

// ---------------- fallback (Round-1 fp32 kernel, proven) — used if ws is too small --------
#define FTK 64
#define FNT (S / FTK)
#define FCAP 120
#define HI_OFF 0.022097086912079608f
#define NITER 50

__global__ __launch_bounds__(NTH, 2) void entmax_attn_fallback(
    const float* __restrict__ query, const float* __restrict__ key,
    const float* __restrict__ value, float* __restrict__ out)
{
    __shared__ float4 sK[FTK * 32];
    __shared__ float4 sQ[ROWS * 32];
    __shared__ int    cIdx[ROWS][FCAP];
    __shared__ float  cVal[ROWS][FCAP];
    __shared__ int    ccnt[ROWS];

    const int tid = threadIdx.x;
    const int bid = blockIdx.x;
    const int b   = bid >> 6;
    const int rb  = bid & 63;

    const float4* Qg = (const float4*)(query + ((size_t)b * S + (size_t)rb * ROWS) * D);
    const float4* Kg = (const float4*)(key + (size_t)b * S * D);

    #pragma unroll
    for (int i = 0; i < 4; i++) {
        int f = tid + NTH * i;
        float4 v = Qg[f];
        v.x *= 0.5f; v.y *= 0.5f; v.z *= 0.5f; v.w *= 0.5f;
        sQ[f] = v;
    }
    if (tid < ROWS) ccnt[tid] = 0;

    const int kg  = tid & 31;
    const int rg  = tid >> 5;
    const int swz = kg & 7;

    float rm[4];
    #pragma unroll
    for (int i = 0; i < 4; i++) rm[i] = -3.0e38f;

    float4 pre[8];
    #pragma unroll
    for (int i = 0; i < 8; i++) pre[i] = Kg[tid + NTH * i];

    for (int t = 0; t < FNT; t++) {
        #pragma unroll
        for (int i = 0; i < 8; i++) {
            int f = tid + NTH * i;
            int kl = f >> 5, dc = f & 31;
            sK[kl * 32 + (dc ^ (kl & 7))] = pre[i];
        }
        if (t + 1 < FNT) {
            #pragma unroll
            for (int i = 0; i < 8; i++) pre[i] = Kg[(t + 1) * (FTK * 32) + tid + NTH * i];
        }
        __syncthreads();

        float acc[4][2] = {{0.f,0.f},{0.f,0.f},{0.f,0.f},{0.f,0.f}};
        #pragma unroll 8
        for (int dc = 0; dc < 32; dc++) {
            int sw = dc ^ swz;
            float4 k0 = sK[kg * 32 + sw];
            float4 k1 = sK[(kg + 32) * 32 + sw];
            #pragma unroll
            for (int i = 0; i < 4; i++) {
                float4 qv = sQ[(rg * 4 + i) * 32 + dc];
                acc[i][0] = fmaf(qv.x, k0.x, acc[i][0]);
                acc[i][0] = fmaf(qv.y, k0.y, acc[i][0]);
                acc[i][0] = fmaf(qv.z, k0.z, acc[i][0]);
                acc[i][0] = fmaf(qv.w, k0.w, acc[i][0]);
                acc[i][1] = fmaf(qv.x, k1.x, acc[i][1]);
                acc[i][1] = fmaf(qv.y, k1.y, acc[i][1]);
                acc[i][1] = fmaf(qv.z, k1.z, acc[i][1]);
                acc[i][1] = fmaf(qv.w, k1.w, acc[i][1]);
            }
        }

        #pragma unroll
        for (int i = 0; i < 4; i++) {
            float m = fmaxf(acc[i][0], acc[i][1]);
            m = fmaxf(m, __shfl_xor(m, 1));
            m = fmaxf(m, __shfl_xor(m, 2));
            m = fmaxf(m, __shfl_xor(m, 4));
            m = fmaxf(m, __shfl_xor(m, 8));
            m = fmaxf(m, __shfl_xor(m, 16));
            rm[i] = fmaxf(rm[i], m);
            float thr = rm[i] - 1.0f;
            #pragma unroll
            for (int j = 0; j < 2; j++) {
                if (acc[i][j] > thr) {
                    int row = rg * 4 + i;
                    int slot = atomicAdd(&ccnt[row], 1);
                    if (slot < FCAP) {
                        cIdx[row][slot] = t * FTK + kg + 32 * j;
                        cVal[row][slot] = acc[i][j];
                    }
                }
            }
        }
        __syncthreads();
    }

    const int wid  = tid >> 6;
    const int lane = tid & 63;
    const float* Vb = value + (size_t)b * S * D;
    float* Ob = out + ((size_t)b * S + (size_t)rb * ROWS) * D;

    #pragma unroll
    for (int r8 = 0; r8 < 8; r8++) {
        int row = wid * 8 + r8;
        int n = min(ccnt[row], FCAP);
        float mx = __shfl(rm[r8 & 3], (r8 & 4) ? 32 : 0);

        float lo = mx - 1.0f;
        float hi = mx - HI_OFF;
        for (int it = 0; it < NITER; it++) {
            float mid = 0.5f * (lo + hi);
            float s = 0.0f;
            for (int c = lane; c < n; c += 64) {
                float tv = fmaxf(cVal[row][c] - mid, 0.0f);
                s = fmaf(tv, tv, s);
            }
            s += __shfl_xor(s, 1); s += __shfl_xor(s, 2); s += __shfl_xor(s, 4);
            s += __shfl_xor(s, 8); s += __shfl_xor(s, 16); s += __shfl_xor(s, 32);
            if (s - 1.0f >= 0.0f) lo = mid; else hi = mid;
        }
        float tau = 0.5f * (lo + hi);

        float z = 0.0f;
        for (int c = lane; c < n; c += 64) {
            float tv = fmaxf(cVal[row][c] - tau, 0.0f);
            float p = tv * tv;
            cVal[row][c] = p;
            z += p;
        }
        z += __shfl_xor(z, 1); z += __shfl_xor(z, 2); z += __shfl_xor(z, 4);
        z += __shfl_xor(z, 8); z += __shfl_xor(z, 16); z += __shfl_xor(z, 32);
        float zinv = 1.0f / z;

        float2 o = make_float2(0.0f, 0.0f);
        for (int c = 0; c < n; c++) {
            float p = cVal[row][c];
            int ii = cIdx[row][c];
            float2 a = ((const float2*)(Vb + (size_t)ii * D))[lane];
            o.x = fmaf(p, a.x, o.x); o.y = fmaf(p, a.y, o.y);
        }
        o.x *= zinv; o.y *= zinv;
        ((float2*)(Ob + (size_t)row * D))[lane] = o;
    }
}

extern "C" void kernel_launch(void* const* d_in, const int* in_sizes, int n_in,
                              void* d_out, int out_size, void* d_ws, size_t ws_size,
                              hipStream_t stream) {
    const float* q = (const float*)d_in[0];
    const float* k = (const float*)d_in[1];
    const float* v = (const float*)d_in[2];
    float* o = (float*)d_out;

    const size_t nelem = (size_t)NB * S * D;              // 2,097,152
    const size_t ws_needed = 2 * nelem * sizeof(unsigned short);  // 8 MB

    if (ws_size >= ws_needed) {
        unsigned short* qb = (unsigned short*)d_ws;
        unsigned short* kb = qb + nelem;
        hipLaunchKernelGGL(convert_kernel, dim3(nelem / 4 / NTH), dim3(NTH), 0, stream,
                           q, k, qb, kb);
        hipLaunchKernelGGL(entmax_mfma_kernel, dim3(NB * (S / ROWS)), dim3(NTH), 0, stream,
                           q, k, v, o, qb, kb);
    } else {
        hipLaunchKernelGGL(entmax_attn_fallback, dim3(NB * (S / ROWS)), dim3(NTH), 0, stream,
                           q, k, v, o);
    }
}